// Round 14
// baseline (232.830 us; speedup 1.0000x reference)
//
#include <hip/hip_runtime.h>
#include <stdint.h>

// ---------------------------------------------------------------------------
// MHA block, round 20.
// r19 post-mortem: long-with-long pairing ~null (47.5->47.1, occ 23.6->24.7)
// -- second attn occupancy miss.  Forced model update: makespan = longest
// block (32 iters); 47.1us/32 = ~3500 cy/iter vs ~300-400 cy of work ->
// attn is FIXED-PER-ITER-COST bound (vmcnt+barrier+serial exp2/pack+issue),
// not bytes/flops.  Shuffling co-residents can't help; amortizing the fixed
// cost can.
// Change (one variable): KVBLK 64 -> 128.  Same total MFMA/exp2/LDS bytes,
// half the iterations.  iters = (qb>>1)+1 -> r19 map becomes EXACTLY
// uniform per CU: {s+1, s+1, 16-s, 16-s}, sum 34, long blocks equal.
// LDS 80KB (K/V dbuf 2x32KB + 16KB Q/P alias) -> 2 blocks/CU = current
// time-avg concurrency, so nothing lost.  gkk = kt*128+i*16+quad*4; even-qb
// last tile's upper half fully masked (~3% waste, never OOB).
// qkv (8-phase, frozen) / o_gemm / cvt r19-identical.
// ---------------------------------------------------------------------------

typedef unsigned short ushort_t;
typedef __attribute__((ext_vector_type(8))) __bf16 bf16x8;   // MFMA A/B operand
typedef __attribute__((ext_vector_type(4))) float floatx4;   // MFMA C/D operand

#define EMBED 1024
#define SEQ   2048
#define NH    16
#define DH    64
#define QK_SCALE 0.18033688011112042f   // 0.125 * log2(e)

// fp32 -> bf16 round-to-nearest-even (finite inputs)
__device__ inline ushort_t f2b(float x) {
  unsigned u = __float_as_uint(x);
  u += 0x7FFFu + ((u >> 16) & 1u);
  return (ushort_t)(u >> 16);
}

// pack bf16(a) | bf16(b)<<16 with +0x8000 round: 2 add + 1 perm
__device__ inline unsigned pk2(float a, float b) {
  unsigned ua = __float_as_uint(a) + 0x8000u;
  unsigned ub = __float_as_uint(b) + 0x8000u;
  return __builtin_amdgcn_perm(ub, ua, 0x07060302u);   // [a2,a3,b2,b3]
}

// async global->LDS, 16B/lane; LDS dest = wave-uniform base (+ lane*16 by HW)
__device__ inline void gl_lds16(const ushort_t* g, ushort_t* l) {
  __builtin_amdgcn_global_load_lds(
      (const __attribute__((address_space(1))) unsigned int*)g,
      (__attribute__((address_space(3))) unsigned int*)l, 16, 0, 0);
}

// ---------------------------------------------------------------------------
// fp32 -> bf16 bulk convert, with per-chunk scale (folds QK scale into Wq)
// ---------------------------------------------------------------------------
struct CvtArgs {
  const float* src[16];
  ushort_t*    dst[16];
  float        scale[16];
};

__global__ __launch_bounds__(256) void cvt_kernel(CvtArgs a) {
  const int chunk = blockIdx.x >> 9;
  const int off = ((blockIdx.x & 511) << 11) + (threadIdx.x << 3);
  const float sc = a.scale[chunk];
  const float4* s = (const float4*)(a.src[chunk] + off);
  float4 f0 = s[0], f1 = s[1];
  union { ushort_t u[8]; uint4 v; } o;
  o.u[0] = f2b(f0.x * sc); o.u[1] = f2b(f0.y * sc);
  o.u[2] = f2b(f0.z * sc); o.u[3] = f2b(f0.w * sc);
  o.u[4] = f2b(f1.x * sc); o.u[5] = f2b(f1.y * sc);
  o.u[6] = f2b(f1.z * sc); o.u[7] = f2b(f1.w * sc);
  *(uint4*)(a.dst[chunk] + off) = o.v;
}

// ---------------------------------------------------------------------------
// Shared epilogue: write one 16x16 C subtile from C-layout accumulator.
//   mode 0 = bf16 row-major, 1 = f32 row-major, 2 = bf16 into VpT[b][h][d][s]
// ---------------------------------------------------------------------------
__device__ inline void store_sub(char* __restrict__ Cv, const int mode,
                                 const int ldc, const int row, const int col,
                                 const floatx4& acc) {
  if (mode == 0) {
    ushort_t* C = (ushort_t*)Cv;
#pragma unroll
    for (int r = 0; r < 4; ++r)
      C[(size_t)(row + r) * ldc + col] = f2b(acc[r]);
  } else if (mode == 1) {
    float* C = (float*)Cv;
#pragma unroll
    for (int r = 0; r < 4; ++r)
      C[(size_t)(row + r) * ldc + col] = acc[r];
  } else {
    // VpT[b][h][d][s]: r -> consecutive s, one 8B store
    ushort_t* C = (ushort_t*)Cv;
    const int b = row >> 11, s = row & 2047;
    const int h = col >> 6, d = col & 63;
    uint2 pk;
    pk.x = pk2(acc[0], acc[1]);
    pk.y = pk2(acc[2], acc[3]);
    *(uint2*)&C[(size_t)((b * NH + h) * DH + d) * SEQ + s] = pk;
  }
}

// ---------------------------------------------------------------------------
// 8-phase 512-thread GEMM core: C[m,n] = sum_k A[m,k]*W[n,k], K=1024 fixed.
// BM=BN=256, BK=64.  8 waves as 2M x 4N; wave owns 128x64 (8x4 subtiles).
// Fragment-ordered LDS chunks (1KB each; lane reads linear 16B -> 0 bank
// conflicts).  Per K-step, 4 phases; phase issues 2 gl_lds of the NEXT
// tile, reads its frag chunks, barriers, 16 MFMA under setprio.  vmcnt(4)
// before the trailing barrier of phases 1 & 3 keeps 4 loads in flight
// across barriers.  (r18-verified: qkv ~47us.)
// ---------------------------------------------------------------------------
__device__ inline void stage_pair(const ushort_t* __restrict__ A,
                                  const ushort_t* __restrict__ W,
                                  const int m0, const int n0, const int k0,
                                  ushort_t* __restrict__ Asb,
                                  ushort_t* __restrict__ Bsb,
                                  const int wid, const int lm, const int quad,
                                  const int pair) {
#pragma unroll
  for (int e = 0; e < 2; ++e) {
    const int ul = (pair < 2) ? (pair * 4 + e * 2)          // 0,2 / 4,6  (half0)
                              : ((pair - 2) * 4 + e * 2 + 1); // 1,3 / 5,7  (half1)
    const int c  = wid * 8 + ul;       // 0..63; <32 = A chunks, else B
    const int cb = c & 31;
    const int sub = cb >> 1;
    const int kc  = (cb & 1) * 32 + quad * 8;
    if (c < 32)
      gl_lds16(A + (size_t)(m0 + sub * 16 + lm) * EMBED + k0 + kc, &Asb[cb * 512]);
    else
      gl_lds16(W + (size_t)(n0 + sub * 16 + lm) * EMBED + k0 + kc, &Bsb[cb * 512]);
  }
}

__device__ inline void gemm512_8ph(const ushort_t* __restrict__ A,
                                   const ushort_t* __restrict__ W,
                                   char* __restrict__ Cv, const int mode,
                                   const int ldc, const int m0, const int n0) {
  __shared__ ushort_t As[2][32 * 512];   // 2 x 32KB
  __shared__ ushort_t Bs[2][32 * 512];   // 2 x 32KB
  const int tid  = threadIdx.x;
  const int lane = tid & 63;
  const int wid  = tid >> 6;          // 0..7
  const int lm   = lane & 15;
  const int quad = lane >> 4;
  const int wm2  = wid >> 2;          // 0..1  (M half: 128 rows)
  const int wn4  = wid & 3;           // 0..3  (N quarter: 64 cols)

  floatx4 zero = {0.f, 0.f, 0.f, 0.f};
  floatx4 acc[8][4];
#pragma unroll
  for (int i = 0; i < 8; ++i)
#pragma unroll
    for (int j = 0; j < 4; ++j) acc[i][j] = zero;

  // prologue: stage tile 0 (halves in order), wait half0, barrier
#pragma unroll
  for (int p = 0; p < 4; ++p)
    stage_pair(A, W, m0, n0, 0, As[0], Bs[0], wid, lm, quad, p);
  asm volatile("s_waitcnt vmcnt(4)" ::: "memory");
  asm volatile("s_barrier" ::: "memory");

#pragma unroll 1
  for (int t = 0; t < 16; ++t) {
    const int cur = t & 1;
    ushort_t* Ac = As[cur];
    ushort_t* Bc = Bs[cur];
    ushort_t* An = As[cur ^ 1];
    ushort_t* Bn = Bs[cur ^ 1];
    const int kn = (t + 1) << 6;
    const bool pf = (t < 15);

    bf16x8 a[4], b[4];

    // ---- phase 0: ks=0, mh=0 ----
#pragma unroll
    for (int i = 0; i < 4; ++i)
      a[i] = *(const bf16x8*)&Ac[((wm2 * 8 + i) * 2 + 0) * 512 + lane * 8];
#pragma unroll
    for (int j = 0; j < 4; ++j)
      b[j] = *(const bf16x8*)&Bc[((wn4 * 4 + j) * 2 + 0) * 512 + lane * 8];
    if (pf) stage_pair(A, W, m0, n0, kn, An, Bn, wid, lm, quad, 0);
    asm volatile("s_barrier" ::: "memory");
    __builtin_amdgcn_s_setprio(1);
#pragma unroll
    for (int i = 0; i < 4; ++i)
#pragma unroll
      for (int j = 0; j < 4; ++j)
        acc[i][j] = __builtin_amdgcn_mfma_f32_16x16x32_bf16(a[i], b[j], acc[i][j], 0, 0, 0);
    __builtin_amdgcn_s_setprio(0);
    asm volatile("s_barrier" ::: "memory");

    // ---- phase 1: ks=0, mh=1 (reuse b) ----
#pragma unroll
    for (int i = 0; i < 4; ++i)
      a[i] = *(const bf16x8*)&Ac[((wm2 * 8 + 4 + i) * 2 + 0) * 512 + lane * 8];
    if (pf) stage_pair(A, W, m0, n0, kn, An, Bn, wid, lm, quad, 1);
    asm volatile("s_barrier" ::: "memory");
    __builtin_amdgcn_s_setprio(1);
#pragma unroll
    for (int i = 0; i < 4; ++i)
#pragma unroll
      for (int j = 0; j < 4; ++j)
        acc[4 + i][j] = __builtin_amdgcn_mfma_f32_16x16x32_bf16(a[i], b[j], acc[4 + i][j], 0, 0, 0);
    __builtin_amdgcn_s_setprio(0);
    // guard cur.half1 for phases 2-3 (my oldest 4 = cur.half1's loads)
    if (pf) asm volatile("s_waitcnt vmcnt(4)" ::: "memory");
    else    asm volatile("s_waitcnt vmcnt(0)" ::: "memory");
    asm volatile("s_barrier" ::: "memory");

    // ---- phase 2: ks=1, mh=0 ----
#pragma unroll
    for (int i = 0; i < 4; ++i)
      a[i] = *(const bf16x8*)&Ac[((wm2 * 8 + i) * 2 + 1) * 512 + lane * 8];
#pragma unroll
    for (int j = 0; j < 4; ++j)
      b[j] = *(const bf16x8*)&Bc[((wn4 * 4 + j) * 2 + 1) * 512 + lane * 8];
    if (pf) stage_pair(A, W, m0, n0, kn, An, Bn, wid, lm, quad, 2);
    asm volatile("s_barrier" ::: "memory");
    __builtin_amdgcn_s_setprio(1);
#pragma unroll
    for (int i = 0; i < 4; ++i)
#pragma unroll
      for (int j = 0; j < 4; ++j)
        acc[i][j] = __builtin_amdgcn_mfma_f32_16x16x32_bf16(a[i], b[j], acc[i][j], 0, 0, 0);
    __builtin_amdgcn_s_setprio(0);
    asm volatile("s_barrier" ::: "memory");

    // ---- phase 3: ks=1, mh=1 (reuse b) ----
#pragma unroll
    for (int i = 0; i < 4; ++i)
      a[i] = *(const bf16x8*)&Ac[((wm2 * 8 + 4 + i) * 2 + 1) * 512 + lane * 8];
    if (pf) stage_pair(A, W, m0, n0, kn, An, Bn, wid, lm, quad, 3);
    asm volatile("s_barrier" ::: "memory");
    __builtin_amdgcn_s_setprio(1);
#pragma unroll
    for (int i = 0; i < 4; ++i)
#pragma unroll
      for (int j = 0; j < 4; ++j)
        acc[4 + i][j] = __builtin_amdgcn_mfma_f32_16x16x32_bf16(a[i], b[j], acc[4 + i][j], 0, 0, 0);
    __builtin_amdgcn_s_setprio(0);
    // guard next.half0 for next step's phases 0-1
    if (pf) asm volatile("s_waitcnt vmcnt(4)" ::: "memory");
    asm volatile("s_barrier" ::: "memory");
  }

#pragma unroll
  for (int i = 0; i < 8; ++i) {
    const int row = m0 + wm2 * 128 + i * 16 + quad * 4;
#pragma unroll
    for (int j = 0; j < 4; ++j)
      store_sub(Cv, mode, ldc, row, n0 + wn4 * 64 + j * 16 + lm, acc[i][j]);
  }
}

struct QkvArgs {
  const ushort_t* A[3];
  const ushort_t* W[3];
  char*           C[3];
};

// grid (16,4,3) = 192 blocks, single round on 256 CUs.
__global__ __launch_bounds__(512, 2) void qkv_gemm(QkvArgs q) {
  const int z = blockIdx.z;
  gemm512_8ph(q.A[z], q.W[z], q.C[z], z == 2 ? 2 : 0, EMBED,
              blockIdx.x * 256, blockIdx.y * 256);
}

// ---------------------------------------------------------------------------
// O-projection GEMM (r10): BM=128, BN=64, BK=64, 256 thr (4 waves 2m x 2n,
// each wave 64x32 = 4x2 subtiles).  Grid (32,16) = 512 blocks = 2 blocks/CU,
// 8 waves/CU in 2 independent barrier domains.  LDS 24KB.
// ---------------------------------------------------------------------------
__global__ __launch_bounds__(256, 4) void o_gemm(const ushort_t* __restrict__ A,
                                                 const ushort_t* __restrict__ W,
                                                 float* __restrict__ C) {
  __shared__ ushort_t As[16 * 512];   // 128 x 64, fragment-ordered
  __shared__ ushort_t Bs[8 * 512];    // 64 x 64
  const int m0 = blockIdx.x * 128, n0 = blockIdx.y * 64;
  const int tid  = threadIdx.x;
  const int lane = tid & 63;
  const int wid  = tid >> 6;          // 0..3
  const int lm   = lane & 15;
  const int quad = lane >> 4;
  const int wm   = wid >> 1;          // 0..1
  const int wn   = wid & 1;           // 0..1

  floatx4 zero = {0.f, 0.f, 0.f, 0.f};
  floatx4 acc[4][2];
#pragma unroll
  for (int i = 0; i < 4; ++i)
#pragma unroll
    for (int j = 0; j < 2; ++j) acc[i][j] = zero;

  for (int k0 = 0; k0 < EMBED; k0 += 64) {
    __syncthreads();
#pragma unroll
    for (int u = 0; u < 6; ++u) {
      const int c   = wid * 6 + u;     // 0..23, wave-uniform
      const int cb  = (c < 16) ? c : (c - 16);
      const int sub = cb >> 1;
      const int kc  = (cb & 1) * 32 + quad * 8;
      if (c < 16)
        gl_lds16(A + (size_t)(m0 + sub * 16 + lm) * EMBED + k0 + kc, &As[cb * 512]);
      else
        gl_lds16(W + (size_t)(n0 + sub * 16 + lm) * EMBED + k0 + kc, &Bs[cb * 512]);
    }
    __syncthreads();   // vmcnt drain -> LDS visible

#pragma unroll
    for (int ks = 0; ks < 2; ++ks) {
      bf16x8 a[4], b[2];
#pragma unroll
      for (int i = 0; i < 4; ++i)
        a[i] = *(const bf16x8*)&As[((wm * 4 + i) * 2 + ks) * 512 + lane * 8];
#pragma unroll
      for (int j = 0; j < 2; ++j)
        b[j] = *(const bf16x8*)&Bs[((wn * 2 + j) * 2 + ks) * 512 + lane * 8];
#pragma unroll
      for (int i = 0; i < 4; ++i)
#pragma unroll
        for (int j = 0; j < 2; ++j)
          acc[i][j] = __builtin_amdgcn_mfma_f32_16x16x32_bf16(a[i], b[j], acc[i][j], 0, 0, 0);
    }
  }

#pragma unroll
  for (int i = 0; i < 4; ++i) {
    const int row = m0 + wm * 64 + i * 16 + quad * 4;
#pragma unroll
    for (int j = 0; j < 2; ++j) {
      const int col = n0 + wn * 32 + j * 16 + lm;
#pragma unroll
      for (int r = 0; r < 4; ++r)
        C[(size_t)(row + r) * EMBED + col] = acc[i][j][r];
    }
  }
}

// ---------------------------------------------------------------------------
// Causal flash attention, S^T formulation, fixed-shift softmax, K/V dbuf.
// r20: KVBLK=128.  Grid 1024 x 256thr (4 waves).  Block = 64 q-cols of one
// (b,h); wave owns 16 q.  iters = (qb>>1)+1 -> qb map {2s,2s+1,30-2s,31-2s}
// gives per-CU iter sets {s+1,s+1,16-s,16-s}: sum 34, long blocks EQUAL.
// LDS 80KB (QsP 16KB alias + K/V dbuf 2x32KB) -> 2 blocks/CU (= prior
// time-avg concurrency).  gkk = kt*128+i*16+quad*4; even-qb last tile's
// upper 64 kv fully masked (~3% waste, never OOB: 15*128+127 = 2047).
// ---------------------------------------------------------------------------
__global__ __launch_bounds__(256, 4) void attn_kernel(const ushort_t* __restrict__ Qp,
                                                      const ushort_t* __restrict__ Kp,
                                                      const ushort_t* __restrict__ VpT,
                                                      ushort_t* __restrict__ Ob) {
  __shared__ ushort_t QsP[16 * 512];     // 16KB: Q 8KB (chunks 0..7) + P alias
  __shared__ ushort_t Ks[2][16 * 512];   // dbuf: 128 kk x 64 d (32KB each pair)
  __shared__ ushort_t VTs[2][16 * 512];  // dbuf: 64 d x 128 kk
  const int L = blockIdx.x;              // 0..1023
  const int s8 = (L >> 5) & 7;
  const int g  = L >> 8;                 // 0..3
  const int qb = (g == 0) ? (2 * s8)
               : (g == 1) ? (2 * s8 + 1)
               : (g == 2) ? (30 - 2 * s8)
                          : (31 - 2 * s8);
  const int bh = L & 31;
  const int h = bh & (NH - 1), b = bh >> 4;
  const int tid = threadIdx.x, lane = tid & 63, wid = tid >> 6;
  const int lm = lane & 15, quad = lane >> 4;
  const size_t qkbase = ((size_t)b * SEQ) * EMBED + h * DH;
  const size_t vtbase = ((size_t)(b * NH + h)) * DH * SEQ;

  // Q staging: 8 chunks of 512; wave's pair c = wid*2 + u covers its 16 q.
#pragma unroll
  for (int u = 0; u < 2; ++u) {
    const int c = wid * 2 + u;
    gl_lds16(Qp + qkbase + (size_t)(qb * 64 + (c >> 1) * 16 + lm) * EMBED
                 + (c & 1) * 32 + quad * 8,
             &QsP[c * 512]);
  }
  // issue K/V tile 0 into buf 0: 32 chunks, 8 per wave.
  // K chunk t (t<16): kk-sub t>>1, d-half t&1.  V chunk tt (t>=16, tt=t-16):
  // d-sub tt>>2, kk-slice tt&3.
#pragma unroll
  for (int u = 0; u < 8; ++u) {
    const int t = wid * 8 + u;
    if (t < 16) {
      const int sub = t >> 1, half = t & 1;
      gl_lds16(Kp + qkbase + (size_t)(sub * 16 + lm) * EMBED + half * 32 + quad * 8,
               &Ks[0][t * 512]);
    } else {
      const int tt = t - 16, sub = tt >> 2, sl = tt & 3;
      gl_lds16(VpT + vtbase + (size_t)(sub * 16 + lm) * SEQ + sl * 32 + quad * 8,
               &VTs[0][tt * 512]);
    }
  }
  asm volatile("s_waitcnt vmcnt(8)" ::: "memory");   // my 2 Q chunks landed
  bf16x8 qf[2];   // [ks]
#pragma unroll
  for (int ks = 0; ks < 2; ++ks)
    qf[ks] = *(const bf16x8*)&QsP[(wid * 2 + ks) * 512 + lane * 8];
  // Q region consumed; wave's 4KB slice of QsP is now P^T scratch.
  ushort_t* pwb = &QsP[wid * 2048];

  float l_part = 0.f;
  floatx4 zero = {0.f, 0.f, 0.f, 0.f};
  floatx4 o_acc[4];
#pragma unroll
  for (int d = 0; d < 4; ++d) o_acc[d] = zero;

  const int kte = qb >> 1;   // last kv-tile index (128-wide tiles)
  for (int kt = 0; kt <= kte; ++kt) {
    const int cur = kt & 1;
    // my K/V[cur] loads (issued last iter / preamble) have landed by now
    asm volatile("s_waitcnt vmcnt(0)" ::: "memory");
    __syncthreads();   // all waves' cur loads landed; all done reading buf cur^1
    if (kt < kte) {
      const int kn = kt + 1;
#pragma unroll
      for (int u = 0; u < 8; ++u) {
        const int t = wid * 8 + u;
        if (t < 16) {
          const int sub = t >> 1, half = t & 1;
          gl_lds16(Kp + qkbase + (size_t)(kn * 128 + sub * 16 + lm) * EMBED
                       + half * 32 + quad * 8,
                   &Ks[cur ^ 1][t * 512]);
        } else {
          const int tt = t - 16, sub = tt >> 2, sl = tt & 3;
          gl_lds16(VpT + vtbase + (size_t)(sub * 16 + lm) * SEQ
                       + kn * 128 + sl * 32 + quad * 8,
                   &VTs[cur ^ 1][tt * 512]);
        }
      }
    }

    // S^T = K Q^T (log2e domain): s_acc[i], i = kk-subtile 0..7
    floatx4 s_acc[8];
#pragma unroll
    for (int i = 0; i < 8; ++i) s_acc[i] = zero;
#pragma unroll
    for (int ks = 0; ks < 2; ++ks)
#pragma unroll
      for (int i = 0; i < 8; ++i) {
        bf16x8 kf = *(const bf16x8*)&Ks[cur][(i * 2 + ks) * 512 + lane * 8];
        s_acc[i] = __builtin_amdgcn_mfma_f32_16x16x32_bf16(kf, qf[ks], s_acc[i], 0, 0, 0);
      }

    // exp2, diagonal mask, l accumulate, pack P^T into wave-private scratch
    const bool diag = (kt == kte);   // uniform branch; last iter only
#pragma unroll
    for (int i = 0; i < 8; ++i) {
      const int sH = i >> 1;
      const int quadB = ((i & 1) << 1) | (quad >> 1);
      const int gkk = kt * 128 + i * 16 + quad * 4;
      float p[4];
#pragma unroll
      for (int r = 0; r < 4; ++r) p[r] = __builtin_amdgcn_exp2f(s_acc[i][r]);
      if (diag) {
        const int gq = qb * 64 + wid * 16 + lm;
#pragma unroll
        for (int r = 0; r < 4; ++r)
          if (gkk + r > gq) p[r] = 0.f;
      }
#pragma unroll
      for (int r = 0; r < 4; ++r) l_part += p[r];
      uint2 pk;
      pk.x = pk2(p[0], p[1]);
      pk.y = pk2(p[2], p[3]);
      *(uint2*)&pwb[sH * 512 + (quadB * 16 + lm) * 8 + ((quad & 1) << 2)] = pk;
    }
    asm volatile("s_waitcnt lgkmcnt(0)" ::: "memory");   // wave-local RAW fence

    // O^T += V^T P^T  (4 kk-slices of 32)
#pragma unroll
    for (int sH = 0; sH < 4; ++sH) {
      bf16x8 pf = *(const bf16x8*)&pwb[sH * 512 + lane * 8];
#pragma unroll
      for (int d = 0; d < 4; ++d) {
        bf16x8 vf = *(const bf16x8*)&VTs[cur][(d * 4 + sH) * 512 + lane * 8];
        o_acc[d] = __builtin_amdgcn_mfma_f32_16x16x32_bf16(vf, pf, o_acc[d], 0, 0, 0);
      }
    }
  }

  // epilogue
  {
    float l = l_part;
    l += __shfl_xor(l, 16, 64);
    l += __shfl_xor(l, 32, 64);
    const float inv_l = 1.0f / l;
    const size_t orow = qkbase + (size_t)(qb * 64 + wid * 16 + lm) * EMBED;
#pragma unroll
    for (int d = 0; d < 4; ++d) {
      uint2 pk;
      pk.x = pk2(o_acc[d][0] * inv_l, o_acc[d][1] * inv_l);
      pk.y = pk2(o_acc[d][2] * inv_l, o_acc[d][3] * inv_l);
      *(uint2*)&Ob[orow + d * 16 + quad * 4] = pk;
    }
  }
}

// ---------------------------------------------------------------------------
// launch
// ---------------------------------------------------------------------------
extern "C" void kernel_launch(void* const* d_in, const int* in_sizes, int n_in,
                              void* d_out, int out_size, void* d_ws, size_t ws_size,
                              hipStream_t stream) {
  // setup_inputs() order: key, query, value, mask, Wq, Wk, Wv, Wo
  const float* key   = (const float*)d_in[0];
  const float* query = (const float*)d_in[1];
  const float* value = (const float*)d_in[2];
  // d_in[3] = static causal tril, handled analytically
  const float* Wq = (const float*)d_in[4];
  const float* Wk = (const float*)d_in[5];
  const float* Wv = (const float*)d_in[6];
  const float* Wo = (const float*)d_in[7];

  char* ws = (char*)d_ws;
  const size_t MB = 1024 * 1024;
  ushort_t* Xk  = (ushort_t*)(ws + 0 * MB);    // key   bf16 [4096][1024]
  ushort_t* Xq  = (ushort_t*)(ws + 8 * MB);    // query bf16
  ushort_t* Xv  = (ushort_t*)(ws + 16 * MB);   // value bf16
  ushort_t* Wqb = (ushort_t*)(ws + 24 * MB);   // pre-scaled by 0.125*log2e
  ushort_t* Wkb = (ushort_t*)(ws + 26 * MB);
  ushort_t* Wvb = (ushort_t*)(ws + 28 * MB);
  ushort_t* Wob = (ushort_t*)(ws + 30 * MB);
  ushort_t* Qp  = (ushort_t*)(ws + 32 * MB);   // projected Q (log2e-scaled)
  ushort_t* Kp  = (ushort_t*)(ws + 40 * MB);
  ushort_t* VpT = (ushort_t*)(ws + 48 * MB);   // [b][h][64][2048]
  ushort_t* Ob  = (ushort_t*)(ws + 56 * MB);   // attention out bf16

  CvtArgs ca;
  const size_t CE = 1048576;
  for (int c = 0; c < 16; ++c) ca.scale[c] = 1.0f;
  for (int c = 0; c < 4; ++c) { ca.src[c]     = key   + c * CE; ca.dst[c]     = Xk + c * CE; }
  for (int c = 0; c < 4; ++c) { ca.src[4 + c] = query + c * CE; ca.dst[4 + c] = Xq + c * CE; }
  for (int c = 0; c < 4; ++c) { ca.src[8 + c] = value + c * CE; ca.dst[8 + c] = Xv + c * CE; }
  ca.src[12] = Wq; ca.dst[12] = Wqb; ca.scale[12] = QK_SCALE;
  ca.src[13] = Wk; ca.dst[13] = Wkb;
  ca.src[14] = Wv; ca.dst[14] = Wvb;
  ca.src[15] = Wo; ca.dst[15] = Wob;
  cvt_kernel<<<8192, 256, 0, stream>>>(ca);

  QkvArgs qa;
  qa.A[0] = Xq; qa.W[0] = Wqb; qa.C[0] = (char*)Qp;
  qa.A[1] = Xk; qa.W[1] = Wkb; qa.C[1] = (char*)Kp;
  qa.A[2] = Xv; qa.W[2] = Wvb; qa.C[2] = (char*)VpT;   // z=2 writes transposed
  qkv_gemm<<<dim3(16, 4, 3), 512, 0, stream>>>(qa);

  attn_kernel<<<1024, 256, 0, stream>>>(Qp, Kp, VpT, Ob);

  o_gemm<<<dim3(32, 16), 256, 0, stream>>>(Ob, Wob, (float*)d_out);
}

// Round 15
// 227.850 us; speedup vs baseline: 1.0219x; 1.0219x over previous
//
#include <hip/hip_runtime.h>
#include <stdint.h>

// ---------------------------------------------------------------------------
// MHA block, round 21 (= r19-exact restore).
// r20 post-mortem: attn KVBLK=128 REGRESSED 47.1->52.3us.  Model wrong both
// ways: per-iter cost SCALES with work (VALUBusy 27->31: serial softmax/pack
// chain doubled with the tile) AND 80KB LDS halved blocks/CU 4->2 (occ
// 24.7->16.4), killing the cross-block TLP that hid the chain.  Third
// consecutive attn structural miss (+r17 setprio null) -> r19 attn is a
// measured local optimum; frozen alongside 8-phase qkv.
// This round: re-bank the best ensemble (r19-exact, measured 227.4us):
//  * qkv: 8-phase 256x256 counted-vmcnt core (r18; ~47us, MfmaUtil 20).
//  * attn: KVBLK=64, 40KB, 4 blocks/CU, long-with-long qb map (r19; 47.1us).
//  * o_gemm: r10 BM=128/BN=64 (512 blocks, 2/CU).
//  * cvt: unchanged.
// Remaining theorized headroom (in-register P exchange in attn; inter-kernel
// gaps) has no validated path -- fusion failed twice, 4 attn levers nulled.
// ---------------------------------------------------------------------------

typedef unsigned short ushort_t;
typedef __attribute__((ext_vector_type(8))) __bf16 bf16x8;   // MFMA A/B operand
typedef __attribute__((ext_vector_type(4))) float floatx4;   // MFMA C/D operand

#define EMBED 1024
#define SEQ   2048
#define NH    16
#define DH    64
#define QK_SCALE 0.18033688011112042f   // 0.125 * log2(e)

// fp32 -> bf16 round-to-nearest-even (finite inputs)
__device__ inline ushort_t f2b(float x) {
  unsigned u = __float_as_uint(x);
  u += 0x7FFFu + ((u >> 16) & 1u);
  return (ushort_t)(u >> 16);
}

// pack bf16(a) | bf16(b)<<16 with +0x8000 round: 2 add + 1 perm
__device__ inline unsigned pk2(float a, float b) {
  unsigned ua = __float_as_uint(a) + 0x8000u;
  unsigned ub = __float_as_uint(b) + 0x8000u;
  return __builtin_amdgcn_perm(ub, ua, 0x07060302u);   // [a2,a3,b2,b3]
}

// async global->LDS, 16B/lane; LDS dest = wave-uniform base (+ lane*16 by HW)
__device__ inline void gl_lds16(const ushort_t* g, ushort_t* l) {
  __builtin_amdgcn_global_load_lds(
      (const __attribute__((address_space(1))) unsigned int*)g,
      (__attribute__((address_space(3))) unsigned int*)l, 16, 0, 0);
}

// ---------------------------------------------------------------------------
// fp32 -> bf16 bulk convert, with per-chunk scale (folds QK scale into Wq)
// ---------------------------------------------------------------------------
struct CvtArgs {
  const float* src[16];
  ushort_t*    dst[16];
  float        scale[16];
};

__global__ __launch_bounds__(256) void cvt_kernel(CvtArgs a) {
  const int chunk = blockIdx.x >> 9;
  const int off = ((blockIdx.x & 511) << 11) + (threadIdx.x << 3);
  const float sc = a.scale[chunk];
  const float4* s = (const float4*)(a.src[chunk] + off);
  float4 f0 = s[0], f1 = s[1];
  union { ushort_t u[8]; uint4 v; } o;
  o.u[0] = f2b(f0.x * sc); o.u[1] = f2b(f0.y * sc);
  o.u[2] = f2b(f0.z * sc); o.u[3] = f2b(f0.w * sc);
  o.u[4] = f2b(f1.x * sc); o.u[5] = f2b(f1.y * sc);
  o.u[6] = f2b(f1.z * sc); o.u[7] = f2b(f1.w * sc);
  *(uint4*)(a.dst[chunk] + off) = o.v;
}

// ---------------------------------------------------------------------------
// Shared epilogue: write one 16x16 C subtile from C-layout accumulator.
//   mode 0 = bf16 row-major, 1 = f32 row-major, 2 = bf16 into VpT[b][h][d][s]
// ---------------------------------------------------------------------------
__device__ inline void store_sub(char* __restrict__ Cv, const int mode,
                                 const int ldc, const int row, const int col,
                                 const floatx4& acc) {
  if (mode == 0) {
    ushort_t* C = (ushort_t*)Cv;
#pragma unroll
    for (int r = 0; r < 4; ++r)
      C[(size_t)(row + r) * ldc + col] = f2b(acc[r]);
  } else if (mode == 1) {
    float* C = (float*)Cv;
#pragma unroll
    for (int r = 0; r < 4; ++r)
      C[(size_t)(row + r) * ldc + col] = acc[r];
  } else {
    // VpT[b][h][d][s]: r -> consecutive s, one 8B store
    ushort_t* C = (ushort_t*)Cv;
    const int b = row >> 11, s = row & 2047;
    const int h = col >> 6, d = col & 63;
    uint2 pk;
    pk.x = pk2(acc[0], acc[1]);
    pk.y = pk2(acc[2], acc[3]);
    *(uint2*)&C[(size_t)((b * NH + h) * DH + d) * SEQ + s] = pk;
  }
}

// ---------------------------------------------------------------------------
// 8-phase 512-thread GEMM core: C[m,n] = sum_k A[m,k]*W[n,k], K=1024 fixed.
// BM=BN=256, BK=64.  8 waves as 2M x 4N; wave owns 128x64 (8x4 subtiles).
// Fragment-ordered LDS chunks (1KB each; lane reads linear 16B -> 0 bank
// conflicts).  Per K-step, 4 phases; phase issues 2 gl_lds of the NEXT
// tile, reads its frag chunks, barriers, 16 MFMA under setprio.  vmcnt(4)
// before the trailing barrier of phases 1 & 3 keeps 4 loads in flight
// across barriers.  (r18-verified: qkv ~47us.)
// ---------------------------------------------------------------------------
__device__ inline void stage_pair(const ushort_t* __restrict__ A,
                                  const ushort_t* __restrict__ W,
                                  const int m0, const int n0, const int k0,
                                  ushort_t* __restrict__ Asb,
                                  ushort_t* __restrict__ Bsb,
                                  const int wid, const int lm, const int quad,
                                  const int pair) {
#pragma unroll
  for (int e = 0; e < 2; ++e) {
    const int ul = (pair < 2) ? (pair * 4 + e * 2)          // 0,2 / 4,6  (half0)
                              : ((pair - 2) * 4 + e * 2 + 1); // 1,3 / 5,7  (half1)
    const int c  = wid * 8 + ul;       // 0..63; <32 = A chunks, else B
    const int cb = c & 31;
    const int sub = cb >> 1;
    const int kc  = (cb & 1) * 32 + quad * 8;
    if (c < 32)
      gl_lds16(A + (size_t)(m0 + sub * 16 + lm) * EMBED + k0 + kc, &Asb[cb * 512]);
    else
      gl_lds16(W + (size_t)(n0 + sub * 16 + lm) * EMBED + k0 + kc, &Bsb[cb * 512]);
  }
}

__device__ inline void gemm512_8ph(const ushort_t* __restrict__ A,
                                   const ushort_t* __restrict__ W,
                                   char* __restrict__ Cv, const int mode,
                                   const int ldc, const int m0, const int n0) {
  __shared__ ushort_t As[2][32 * 512];   // 2 x 32KB
  __shared__ ushort_t Bs[2][32 * 512];   // 2 x 32KB
  const int tid  = threadIdx.x;
  const int lane = tid & 63;
  const int wid  = tid >> 6;          // 0..7
  const int lm   = lane & 15;
  const int quad = lane >> 4;
  const int wm2  = wid >> 2;          // 0..1  (M half: 128 rows)
  const int wn4  = wid & 3;           // 0..3  (N quarter: 64 cols)

  floatx4 zero = {0.f, 0.f, 0.f, 0.f};
  floatx4 acc[8][4];
#pragma unroll
  for (int i = 0; i < 8; ++i)
#pragma unroll
    for (int j = 0; j < 4; ++j) acc[i][j] = zero;

  // prologue: stage tile 0 (halves in order), wait half0, barrier
#pragma unroll
  for (int p = 0; p < 4; ++p)
    stage_pair(A, W, m0, n0, 0, As[0], Bs[0], wid, lm, quad, p);
  asm volatile("s_waitcnt vmcnt(4)" ::: "memory");
  asm volatile("s_barrier" ::: "memory");

#pragma unroll 1
  for (int t = 0; t < 16; ++t) {
    const int cur = t & 1;
    ushort_t* Ac = As[cur];
    ushort_t* Bc = Bs[cur];
    ushort_t* An = As[cur ^ 1];
    ushort_t* Bn = Bs[cur ^ 1];
    const int kn = (t + 1) << 6;
    const bool pf = (t < 15);

    bf16x8 a[4], b[4];

    // ---- phase 0: ks=0, mh=0 ----
#pragma unroll
    for (int i = 0; i < 4; ++i)
      a[i] = *(const bf16x8*)&Ac[((wm2 * 8 + i) * 2 + 0) * 512 + lane * 8];
#pragma unroll
    for (int j = 0; j < 4; ++j)
      b[j] = *(const bf16x8*)&Bc[((wn4 * 4 + j) * 2 + 0) * 512 + lane * 8];
    if (pf) stage_pair(A, W, m0, n0, kn, An, Bn, wid, lm, quad, 0);
    asm volatile("s_barrier" ::: "memory");
    __builtin_amdgcn_s_setprio(1);
#pragma unroll
    for (int i = 0; i < 4; ++i)
#pragma unroll
      for (int j = 0; j < 4; ++j)
        acc[i][j] = __builtin_amdgcn_mfma_f32_16x16x32_bf16(a[i], b[j], acc[i][j], 0, 0, 0);
    __builtin_amdgcn_s_setprio(0);
    asm volatile("s_barrier" ::: "memory");

    // ---- phase 1: ks=0, mh=1 (reuse b) ----
#pragma unroll
    for (int i = 0; i < 4; ++i)
      a[i] = *(const bf16x8*)&Ac[((wm2 * 8 + 4 + i) * 2 + 0) * 512 + lane * 8];
    if (pf) stage_pair(A, W, m0, n0, kn, An, Bn, wid, lm, quad, 1);
    asm volatile("s_barrier" ::: "memory");
    __builtin_amdgcn_s_setprio(1);
#pragma unroll
    for (int i = 0; i < 4; ++i)
#pragma unroll
      for (int j = 0; j < 4; ++j)
        acc[4 + i][j] = __builtin_amdgcn_mfma_f32_16x16x32_bf16(a[i], b[j], acc[4 + i][j], 0, 0, 0);
    __builtin_amdgcn_s_setprio(0);
    // guard cur.half1 for phases 2-3 (my oldest 4 = cur.half1's loads)
    if (pf) asm volatile("s_waitcnt vmcnt(4)" ::: "memory");
    else    asm volatile("s_waitcnt vmcnt(0)" ::: "memory");
    asm volatile("s_barrier" ::: "memory");

    // ---- phase 2: ks=1, mh=0 ----
#pragma unroll
    for (int i = 0; i < 4; ++i)
      a[i] = *(const bf16x8*)&Ac[((wm2 * 8 + i) * 2 + 1) * 512 + lane * 8];
#pragma unroll
    for (int j = 0; j < 4; ++j)
      b[j] = *(const bf16x8*)&Bc[((wn4 * 4 + j) * 2 + 1) * 512 + lane * 8];
    if (pf) stage_pair(A, W, m0, n0, kn, An, Bn, wid, lm, quad, 2);
    asm volatile("s_barrier" ::: "memory");
    __builtin_amdgcn_s_setprio(1);
#pragma unroll
    for (int i = 0; i < 4; ++i)
#pragma unroll
      for (int j = 0; j < 4; ++j)
        acc[i][j] = __builtin_amdgcn_mfma_f32_16x16x32_bf16(a[i], b[j], acc[i][j], 0, 0, 0);
    __builtin_amdgcn_s_setprio(0);
    asm volatile("s_barrier" ::: "memory");

    // ---- phase 3: ks=1, mh=1 (reuse b) ----
#pragma unroll
    for (int i = 0; i < 4; ++i)
      a[i] = *(const bf16x8*)&Ac[((wm2 * 8 + 4 + i) * 2 + 1) * 512 + lane * 8];
    if (pf) stage_pair(A, W, m0, n0, kn, An, Bn, wid, lm, quad, 3);
    asm volatile("s_barrier" ::: "memory");
    __builtin_amdgcn_s_setprio(1);
#pragma unroll
    for (int i = 0; i < 4; ++i)
#pragma unroll
      for (int j = 0; j < 4; ++j)
        acc[4 + i][j] = __builtin_amdgcn_mfma_f32_16x16x32_bf16(a[i], b[j], acc[4 + i][j], 0, 0, 0);
    __builtin_amdgcn_s_setprio(0);
    // guard next.half0 for next step's phases 0-1
    if (pf) asm volatile("s_waitcnt vmcnt(4)" ::: "memory");
    asm volatile("s_barrier" ::: "memory");
  }

#pragma unroll
  for (int i = 0; i < 8; ++i) {
    const int row = m0 + wm2 * 128 + i * 16 + quad * 4;
#pragma unroll
    for (int j = 0; j < 4; ++j)
      store_sub(Cv, mode, ldc, row, n0 + wn4 * 64 + j * 16 + lm, acc[i][j]);
  }
}

struct QkvArgs {
  const ushort_t* A[3];
  const ushort_t* W[3];
  char*           C[3];
};

// grid (16,4,3) = 192 blocks, single round on 256 CUs.
__global__ __launch_bounds__(512, 2) void qkv_gemm(QkvArgs q) {
  const int z = blockIdx.z;
  gemm512_8ph(q.A[z], q.W[z], q.C[z], z == 2 ? 2 : 0, EMBED,
              blockIdx.x * 256, blockIdx.y * 256);
}

// ---------------------------------------------------------------------------
// O-projection GEMM (r10): BM=128, BN=64, BK=64, 256 thr (4 waves 2m x 2n,
// each wave 64x32 = 4x2 subtiles).  Grid (32,16) = 512 blocks = 2 blocks/CU,
// 8 waves/CU in 2 independent barrier domains.  LDS 24KB.
// ---------------------------------------------------------------------------
__global__ __launch_bounds__(256, 4) void o_gemm(const ushort_t* __restrict__ A,
                                                 const ushort_t* __restrict__ W,
                                                 float* __restrict__ C) {
  __shared__ ushort_t As[16 * 512];   // 128 x 64, fragment-ordered
  __shared__ ushort_t Bs[8 * 512];    // 64 x 64
  const int m0 = blockIdx.x * 128, n0 = blockIdx.y * 64;
  const int tid  = threadIdx.x;
  const int lane = tid & 63;
  const int wid  = tid >> 6;          // 0..3
  const int lm   = lane & 15;
  const int quad = lane >> 4;
  const int wm   = wid >> 1;          // 0..1
  const int wn   = wid & 1;           // 0..1

  floatx4 zero = {0.f, 0.f, 0.f, 0.f};
  floatx4 acc[4][2];
#pragma unroll
  for (int i = 0; i < 4; ++i)
#pragma unroll
    for (int j = 0; j < 2; ++j) acc[i][j] = zero;

  for (int k0 = 0; k0 < EMBED; k0 += 64) {
    __syncthreads();
#pragma unroll
    for (int u = 0; u < 6; ++u) {
      const int c   = wid * 6 + u;     // 0..23, wave-uniform
      const int cb  = (c < 16) ? c : (c - 16);
      const int sub = cb >> 1;
      const int kc  = (cb & 1) * 32 + quad * 8;
      if (c < 16)
        gl_lds16(A + (size_t)(m0 + sub * 16 + lm) * EMBED + k0 + kc, &As[cb * 512]);
      else
        gl_lds16(W + (size_t)(n0 + sub * 16 + lm) * EMBED + k0 + kc, &Bs[cb * 512]);
    }
    __syncthreads();   // vmcnt drain -> LDS visible

#pragma unroll
    for (int ks = 0; ks < 2; ++ks) {
      bf16x8 a[4], b[2];
#pragma unroll
      for (int i = 0; i < 4; ++i)
        a[i] = *(const bf16x8*)&As[((wm * 4 + i) * 2 + ks) * 512 + lane * 8];
#pragma unroll
      for (int j = 0; j < 2; ++j)
        b[j] = *(const bf16x8*)&Bs[((wn * 2 + j) * 2 + ks) * 512 + lane * 8];
#pragma unroll
      for (int i = 0; i < 4; ++i)
#pragma unroll
        for (int j = 0; j < 2; ++j)
          acc[i][j] = __builtin_amdgcn_mfma_f32_16x16x32_bf16(a[i], b[j], acc[i][j], 0, 0, 0);
    }
  }

#pragma unroll
  for (int i = 0; i < 4; ++i) {
    const int row = m0 + wm * 64 + i * 16 + quad * 4;
#pragma unroll
    for (int j = 0; j < 2; ++j) {
      const int col = n0 + wn * 32 + j * 16 + lm;
#pragma unroll
      for (int r = 0; r < 4; ++r)
        C[(size_t)(row + r) * EMBED + col] = acc[i][j][r];
    }
  }
}

// ---------------------------------------------------------------------------
// Causal flash attention, S^T formulation, fixed-shift softmax, K/V dbuf.
// Grid 1024 x 256thr (4 waves).  Block = 64 q-cols of one (b,h); wave owns
// 16 q.  KT=64.  One barrier per iter; next K/V tile's global_load_lds
// issued right after the barrier, landing during compute.
// LDS 40KB -> 4 blocks/CU (16 waves/CU, 4/SIMD from 4 independent blocks).
// r19 qb map (long-with-long): slot s=(L>>5)&7, group g=L>>8:
//   {2s, 2s+1, 30-2s, 31-2s} -> the 4 blocks sharing a CU sum to 66 iters
// AND the two longest differ by 1 iter.  bh stays in L&31 -> same-head L2
// pinning and 4-blocks-share-one-head preserved.  (Measured 47.1us; frozen:
// KVBLK=128 regressed, setprio null, pairing variants null.)
// ---------------------------------------------------------------------------
__global__ __launch_bounds__(256, 4) void attn_kernel(const ushort_t* __restrict__ Qp,
                                                      const ushort_t* __restrict__ Kp,
                                                      const ushort_t* __restrict__ VpT,
                                                      ushort_t* __restrict__ Ob) {
  __shared__ ushort_t Qs[8 * 512];       // 64 q x 64 d; aliased as P scratch
  __shared__ ushort_t Ks[2][8 * 512];    // dbuf: 64 kk x 64 d
  __shared__ ushort_t VTs[2][8 * 512];   // dbuf: 64 d x 64 kk
  const int L = blockIdx.x;              // 0..1023
  const int s8 = (L >> 5) & 7;
  const int g  = L >> 8;                 // 0..3
  const int qb = (g == 0) ? (2 * s8)
               : (g == 1) ? (2 * s8 + 1)
               : (g == 2) ? (30 - 2 * s8)
                          : (31 - 2 * s8);
  const int bh = L & 31;
  const int h = bh & (NH - 1), b = bh >> 4;
  const int tid = threadIdx.x, lane = tid & 63, wid = tid >> 6;
  const int lm = lane & 15, quad = lane >> 4;
  const size_t qkbase = ((size_t)b * SEQ) * EMBED + h * DH;
  const size_t vtbase = ((size_t)(b * NH + h)) * DH * SEQ;

  // Q staging: 4 chunks of 512; wave's pair c = wid*2 + u covers its 16 q.
#pragma unroll
  for (int u = 0; u < 2; ++u) {
    const int c = wid * 2 + u;
    gl_lds16(Qp + qkbase + (size_t)(qb * 64 + (c >> 1) * 16 + lm) * EMBED
                 + (c & 1) * 32 + quad * 8,
             &Qs[c * 512]);
  }
  // issue K/V for kt=0 into buf 0 (behind the Q loads)
#pragma unroll
  for (int u = 0; u < 4; ++u) {
    const int t = wid * 4 + u;
    const int cb = t & 7, sub = cb >> 1, half = cb & 1;
    if (t < 8)
      gl_lds16(Kp + qkbase + (size_t)(sub * 16 + lm) * EMBED + half * 32 + quad * 8,
               &Ks[0][cb * 512]);
    else
      gl_lds16(VpT + vtbase + (size_t)(sub * 16 + lm) * SEQ + half * 32 + quad * 8,
               &VTs[0][cb * 512]);
  }
  asm volatile("s_waitcnt vmcnt(4)" ::: "memory");   // my Q chunks landed
  bf16x8 qf[2];   // [ks]
#pragma unroll
  for (int ks = 0; ks < 2; ++ks)
    qf[ks] = *(const bf16x8*)&Qs[(wid * 2 + ks) * 512 + lane * 8];
  // Q region is now dead; reuse the wave's own 2KB slice as P scratch.
  ushort_t* pwb = &Qs[wid * 1024];

  float l_part = 0.f;
  floatx4 zero = {0.f, 0.f, 0.f, 0.f};
  floatx4 o_acc[4];
#pragma unroll
  for (int d = 0; d < 4; ++d) o_acc[d] = zero;

  for (int kt = 0; kt <= qb; ++kt) {
    const int cur = kt & 1;
    // my K/V[cur] loads (issued last iter / preamble) have landed by now
    asm volatile("s_waitcnt vmcnt(0)" ::: "memory");
    __syncthreads();   // all waves' cur loads landed; all done reading buf cur^1
    if (kt < qb) {
      const int kn = kt + 1;
#pragma unroll
      for (int u = 0; u < 4; ++u) {
        const int t = wid * 4 + u;
        const int cb = t & 7, sub = cb >> 1, half = cb & 1;
        if (t < 8)
          gl_lds16(Kp + qkbase + (size_t)(kn * 64 + sub * 16 + lm) * EMBED
                       + half * 32 + quad * 8,
                   &Ks[cur ^ 1][cb * 512]);
        else
          gl_lds16(VpT + vtbase + (size_t)(sub * 16 + lm) * SEQ
                       + kn * 64 + half * 32 + quad * 8,
                   &VTs[cur ^ 1][cb * 512]);
      }
    }

    // S^T = K Q^T (log2e domain): s_acc[i], i = kk-subtile 0..3
    floatx4 s_acc[4];
#pragma unroll
    for (int i = 0; i < 4; ++i) s_acc[i] = zero;
#pragma unroll
    for (int ks = 0; ks < 2; ++ks)
#pragma unroll
      for (int i = 0; i < 4; ++i) {
        bf16x8 kf = *(const bf16x8*)&Ks[cur][(i * 2 + ks) * 512 + lane * 8];
        s_acc[i] = __builtin_amdgcn_mfma_f32_16x16x32_bf16(kf, qf[ks], s_acc[i], 0, 0, 0);
      }

    // exp2, diagonal mask, l accumulate, pack P^T into wave-private scratch
    const bool diag = (kt == qb);   // uniform branch; last iter only
#pragma unroll
    for (int i = 0; i < 4; ++i) {
      const int sH = i >> 1;
      const int quadB = ((i & 1) << 1) | (quad >> 1);
      const int gkk = kt * 64 + i * 16 + quad * 4;
      float p[4];
#pragma unroll
      for (int r = 0; r < 4; ++r) p[r] = __builtin_amdgcn_exp2f(s_acc[i][r]);
      if (diag) {
        const int gq = qb * 64 + wid * 16 + lm;
#pragma unroll
        for (int r = 0; r < 4; ++r)
          if (gkk + r > gq) p[r] = 0.f;
      }
#pragma unroll
      for (int r = 0; r < 4; ++r) l_part += p[r];
      uint2 pk;
      pk.x = pk2(p[0], p[1]);
      pk.y = pk2(p[2], p[3]);
      *(uint2*)&pwb[sH * 512 + (quadB * 16 + lm) * 8 + ((quad & 1) << 2)] = pk;
    }
    asm volatile("s_waitcnt lgkmcnt(0)" ::: "memory");   // wave-local RAW fence

    // O^T += V^T P^T
#pragma unroll
    for (int sH = 0; sH < 2; ++sH) {
      bf16x8 pf = *(const bf16x8*)&pwb[sH * 512 + lane * 8];
#pragma unroll
      for (int d = 0; d < 4; ++d) {
        bf16x8 vf = *(const bf16x8*)&VTs[cur][(d * 2 + sH) * 512 + lane * 8];
        o_acc[d] = __builtin_amdgcn_mfma_f32_16x16x32_bf16(vf, pf, o_acc[d], 0, 0, 0);
      }
    }
  }

  // epilogue
  {
    float l = l_part;
    l += __shfl_xor(l, 16, 64);
    l += __shfl_xor(l, 32, 64);
    const float inv_l = 1.0f / l;
    const size_t orow = qkbase + (size_t)(qb * 64 + wid * 16 + lm) * EMBED;
#pragma unroll
    for (int d = 0; d < 4; ++d) {
      uint2 pk;
      pk.x = pk2(o_acc[d][0] * inv_l, o_acc[d][1] * inv_l);
      pk.y = pk2(o_acc[d][2] * inv_l, o_acc[d][3] * inv_l);
      *(uint2*)&Ob[orow + d * 16 + quad * 4] = pk;
    }
  }
}

// ---------------------------------------------------------------------------
// launch
// ---------------------------------------------------------------------------
extern "C" void kernel_launch(void* const* d_in, const int* in_sizes, int n_in,
                              void* d_out, int out_size, void* d_ws, size_t ws_size,
                              hipStream_t stream) {
  // setup_inputs() order: key, query, value, mask, Wq, Wk, Wv, Wo
  const float* key   = (const float*)d_in[0];
  const float* query = (const float*)d_in[1];
  const float* value = (const float*)d_in[2];
  // d_in[3] = static causal tril, handled analytically
  const float* Wq = (const float*)d_in[4];
  const float* Wk = (const float*)d_in[5];
  const float* Wv = (const float*)d_in[6];
  const float* Wo = (const float*)d_in[7];

  char* ws = (char*)d_ws;
  const size_t MB = 1024 * 1024;
  ushort_t* Xk  = (ushort_t*)(ws + 0 * MB);    // key   bf16 [4096][1024]
  ushort_t* Xq  = (ushort_t*)(ws + 8 * MB);    // query bf16
  ushort_t* Xv  = (ushort_t*)(ws + 16 * MB);   // value bf16
  ushort_t* Wqb = (ushort_t*)(ws + 24 * MB);   // pre-scaled by 0.125*log2e
  ushort_t* Wkb = (ushort_t*)(ws + 26 * MB);
  ushort_t* Wvb = (ushort_t*)(ws + 28 * MB);
  ushort_t* Wob = (ushort_t*)(ws + 30 * MB);
  ushort_t* Qp  = (ushort_t*)(ws + 32 * MB);   // projected Q (log2e-scaled)
  ushort_t* Kp  = (ushort_t*)(ws + 40 * MB);
  ushort_t* VpT = (ushort_t*)(ws + 48 * MB);   // [b][h][64][2048]
  ushort_t* Ob  = (ushort_t*)(ws + 56 * MB);   // attention out bf16

  CvtArgs ca;
  const size_t CE = 1048576;
  for (int c = 0; c < 16; ++c) ca.scale[c] = 1.0f;
  for (int c = 0; c < 4; ++c) { ca.src[c]     = key   + c * CE; ca.dst[c]     = Xk + c * CE; }
  for (int c = 0; c < 4; ++c) { ca.src[4 + c] = query + c * CE; ca.dst[4 + c] = Xq + c * CE; }
  for (int c = 0; c < 4; ++c) { ca.src[8 + c] = value + c * CE; ca.dst[8 + c] = Xv + c * CE; }
  ca.src[12] = Wq; ca.dst[12] = Wqb; ca.scale[12] = QK_SCALE;
  ca.src[13] = Wk; ca.dst[13] = Wkb;
  ca.src[14] = Wv; ca.dst[14] = Wvb;
  ca.src[15] = Wo; ca.dst[15] = Wob;
  cvt_kernel<<<8192, 256, 0, stream>>>(ca);

  QkvArgs qa;
  qa.A[0] = Xq; qa.W[0] = Wqb; qa.C[0] = (char*)Qp;
  qa.A[1] = Xk; qa.W[1] = Wkb; qa.C[1] = (char*)Kp;
  qa.A[2] = Xv; qa.W[2] = Wvb; qa.C[2] = (char*)VpT;   // z=2 writes transposed
  qkv_gemm<<<dim3(16, 4, 3), 512, 0, stream>>>(qa);

  attn_kernel<<<1024, 256, 0, stream>>>(Qp, Kp, VpT, Ob);

  o_gemm<<<dim3(32, 16), 256, 0, stream>>>(Ob, Wob, (float*)d_out);
}